// Round 3
// baseline (253.031 us; speedup 1.0000x reference)
//
#include <hip/hip_runtime.h>
#include <hip/hip_bf16.h>
#include <stdint.h>

// ClusterAssignment: out[n,k] = q/(row-sum q), q = 1/(1+||x_n-c_k||^2), ALPHA=1
// N=65536, K=1024, D=512, fp32 in/out.
// R3: B (1MB, L2-resident) loaded global->reg directly (it has zero cross-wave
// reuse; R2 staged it through LDS and the vmcnt(0) barrier drain of 136KB/step
// was the bottleneck: MfmaUtil 17.5%, HBM 2TB/s). LDS now holds only A,
// double-buffered 2x8KB, prefetched one BK=64 panel ahead so the per-2-step
// __syncthreads drain waits on a ~1500-cycle-old load. Fused normalize kept.

#define N_ROWS 65536
#define K_CL   1024
#define D_DIM  512
#define BM     64

typedef __attribute__((ext_vector_type(8))) short short8;
typedef __attribute__((ext_vector_type(4))) float f32x4;

__device__ __forceinline__ ushort f2bf(float f) {
    union { float f; uint32_t u; } v; v.f = f;
    uint32_t u = v.u;
    u += 0x7fffu + ((u >> 16) & 1u);   // RNE (inputs are finite normals)
    return (ushort)(u >> 16);
}

__device__ __forceinline__ float waveReduceSum(float s) {
#pragma unroll
    for (int off = 32; off; off >>= 1) s += __shfl_down(s, off, 64);
    return s;
}

// ---- prep: fp32 -> bf16 + row sum-of-squares (one wave per row of 512) ----
__global__ void prep_rows(const float* __restrict__ X, ushort* __restrict__ Xbf,
                          float* __restrict__ sq) {
    const int row  = blockIdx.x * 4 + (threadIdx.x >> 6);
    const int lane = threadIdx.x & 63;
    const float4* src = (const float4*)(X + (size_t)row * D_DIM);
    float4 a = src[lane * 2];
    float4 b = src[lane * 2 + 1];
    float s = (a.x*a.x + a.y*a.y) + (a.z*a.z + a.w*a.w)
            + (b.x*b.x + b.y*b.y) + (b.z*b.z + b.w*b.w);
    uint4 o;
    o.x = (uint32_t)f2bf(a.x) | ((uint32_t)f2bf(a.y) << 16);
    o.y = (uint32_t)f2bf(a.z) | ((uint32_t)f2bf(a.w) << 16);
    o.z = (uint32_t)f2bf(b.x) | ((uint32_t)f2bf(b.y) << 16);
    o.w = (uint32_t)f2bf(b.z) | ((uint32_t)f2bf(b.w) << 16);
    *(uint4*)(Xbf + (size_t)row * D_DIM + lane * 8) = o;
    s = waveReduceSum(s);
    if (lane == 0) sq[row] = s;
}

// ---- fused GEMM + numerator + row-normalize ----
// Block: 64 rows x full K=1024, 512 threads (8 waves); wave w owns cluster
// cols [w*128, w*128+128). A in LDS (dbuf 2x8KB, XOR-swizzled, R2-verified
// addressing); B direct global->reg. 16 compute steps of BK=32.
__global__ __launch_bounds__(512, 2) void gemm_fused(
    const ushort* __restrict__ A, const ushort* __restrict__ B,
    const float* __restrict__ xsq, const float* __restrict__ csq,
    float* __restrict__ out)
{
    // [row][64] bf16 = 128 B rows; slot s (16B) of row r holds global slot s^(r&7)
    __shared__ __align__(16) ushort smA[2][BM * 64];    // 2 x 8 KB

    const int tid  = threadIdx.x;
    const int w    = tid >> 6;
    const int lane = tid & 63;
    const int l4 = lane >> 4, l16 = lane & 15;
    const int rbase = blockIdx.x * BM;

    // A staging (R2-verified): thread t -> row tid>>3, source slot pre-swizzled
    const int srow  = tid >> 3;
    const int sslot = (tid & 7) ^ (srow & 7);
    const ushort* gA = A + (size_t)(rbase + srow) * D_DIM + sslot * 8;
    ushort* ldsA[2] = { &smA[0][0] + w * 512, &smA[1][0] + w * 512 };

    // B per-lane fragment bases: row (w*128+n*16+l16), k-slice l4*8
    const ushort* gB[8];
#pragma unroll
    for (int n = 0; n < 8; ++n)
        gB[n] = B + (size_t)(w * 128 + n * 16 + l16) * D_DIM + l4 * 8;

    f32x4 acc[4][8] = {};
    const int swz = (l16 & 7) << 4;              // read-side byte swizzle

    // prologue: stage A panel 0 into buf0
    __builtin_amdgcn_global_load_lds(
        (const __attribute__((address_space(1))) void*)gA,
        (__attribute__((address_space(3))) void*)ldsA[0], 16, 0, 0);
    __syncthreads();

#pragma unroll
    for (int s = 0; s < 16; ++s) {
        const int kt  = s * 32;
        const int buf = (s >> 1) & 1;

        // B fragments for this step (compiler pipelines + waits at MFMA use)
        short8 bf[8];
#pragma unroll
        for (int n = 0; n < 8; ++n)
            bf[n] = *(const short8*)(gB[n] + kt);

        // prefetch next A panel (even steps; lands before barrier end of s+1)
        if ((s & 1) == 0 && s < 14)
            __builtin_amdgcn_global_load_lds(
                (const __attribute__((address_space(1))) void*)(gA + kt + 64),
                (__attribute__((address_space(3))) void*)ldsA[buf ^ 1], 16, 0, 0);

        // A fragments from LDS (swizzled read)
        short8 af[4];
        const int cb = (s & 1) * 64;
#pragma unroll
        for (int m = 0; m < 4; ++m) {
            const int row = m * 16 + l16;
            af[m] = *(const short8*)((const char*)&smA[buf][0]
                    + row * 128 + ((cb + l4 * 16) ^ swz));
        }

        __builtin_amdgcn_s_setprio(1);
#pragma unroll
        for (int m = 0; m < 4; ++m)
#pragma unroll
            for (int n = 0; n < 8; ++n)
                acc[m][n] = __builtin_amdgcn_mfma_f32_16x16x32_bf16(
                    af[m], bf[n], acc[m][n], 0, 0, 0);
        __builtin_amdgcn_s_setprio(0);

        // barrier once per A panel; only the A-prefetch (1.5 steps old) is
        // outstanding, so the implicit vmcnt(0) drain is near-free
        if (s & 1) __syncthreads();
    }

    // ---- epilogue: numerator + fused row-normalize ----
    // C/D layout: col = l16, row = l4*4 + reg (per 16x16 frag)
    float xs[4][4];
#pragma unroll
    for (int m = 0; m < 4; ++m)
#pragma unroll
        for (int r = 0; r < 4; ++r)
            xs[m][r] = xsq[rbase + m * 16 + l4 * 4 + r];

    float s[4][4] = {{0.f}};
#pragma unroll
    for (int n = 0; n < 8; ++n) {
        const float cs = csq[w * 128 + n * 16 + l16];
#pragma unroll
        for (int m = 0; m < 4; ++m)
#pragma unroll
            for (int r = 0; r < 4; ++r) {
                float ns = fmaxf(xs[m][r] - 2.0f * acc[m][n][r] + cs, 0.0f);
                float p = 1.0f / (1.0f + ns);
                acc[m][n][r] = p;
                s[m][r] += p;
            }
    }
    // reduce across the 16 col-lanes of each 16-lane group
#pragma unroll
    for (int m = 0; m < 4; ++m)
#pragma unroll
        for (int r = 0; r < 4; ++r) {
            float v = s[m][r];
            v += __shfl_xor(v, 1, 64);
            v += __shfl_xor(v, 2, 64);
            v += __shfl_xor(v, 4, 64);
            v += __shfl_xor(v, 8, 64);
            s[m][r] = v;
        }
    // cross-wave reduce via LDS (alias smA; final loop barrier protects)
    float* smRS  = (float*)&smA[0][0];   // [8 waves][64 rows]
    float* smInv = (float*)&smA[0][0] + 512;   // [64]
    if (l16 == 0) {
#pragma unroll
        for (int m = 0; m < 4; ++m)
#pragma unroll
            for (int r = 0; r < 4; ++r)
                smRS[w * 64 + m * 16 + l4 * 4 + r] = s[m][r];
    }
    __syncthreads();
    if (tid < 64) {
        float t = 0.f;
#pragma unroll
        for (int j = 0; j < 8; ++j) t += smRS[j * 64 + tid];
        smInv[tid] = 1.0f / t;
    }
    __syncthreads();

    float inv[4][4];
#pragma unroll
    for (int m = 0; m < 4; ++m)
#pragma unroll
        for (int r = 0; r < 4; ++r)
            inv[m][r] = smInv[m * 16 + l4 * 4 + r];   // broadcast read

#pragma unroll
    for (int m = 0; m < 4; ++m)
#pragma unroll
        for (int n = 0; n < 8; ++n) {
            const int col = w * 128 + n * 16 + l16;
#pragma unroll
            for (int r = 0; r < 4; ++r) {
                const int row = rbase + m * 16 + l4 * 4 + r;
                out[(size_t)row * K_CL + col] = acc[m][n][r] * inv[m][r];
            }
        }
}

extern "C" void kernel_launch(void* const* d_in, const int* in_sizes, int n_in,
                              void* d_out, int out_size, void* d_ws, size_t ws_size,
                              hipStream_t stream) {
    const float* batch   = (const float*)d_in[0];
    const float* centers = (const float*)d_in[1];
    float* out = (float*)d_out;

    char* ws = (char*)d_ws;
    ushort* Abf = (ushort*)ws;                                          // 64 MB
    ushort* Bbf = (ushort*)(ws + (size_t)N_ROWS * D_DIM * 2);          // 1 MB
    float*  xsq = (float*)(ws + (size_t)N_ROWS * D_DIM * 2
                              + (size_t)K_CL * D_DIM * 2);             // 256 KB
    float*  csq = xsq + N_ROWS;                                         // 4 KB
    (void)in_sizes; (void)n_in; (void)out_size; (void)ws_size;

    prep_rows<<<K_CL / 4,   256, 0, stream>>>(centers, Bbf, csq);
    prep_rows<<<N_ROWS / 4, 256, 0, stream>>>(batch, Abf, xsq);
    gemm_fused<<<N_ROWS / BM, 512, 0, stream>>>(Abf, Bbf, xsq, csq, out);
}

// Round 4
// 228.861 us; speedup vs baseline: 1.1056x; 1.1056x over previous
//
#include <hip/hip_runtime.h>
#include <hip/hip_bf16.h>
#include <stdint.h>

// ClusterAssignment: out[n,k] = q/(row-sum q), q = 1/(1+||x_n-c_k||^2), ALPHA=1
// N=65536, K=1024, D=512, fp32 in/out.
// R4: full-K block (64 x 1024) with T3+T4 schedule: double-buffered LDS
// (B 2x64KB + A 2x4KB = 136KB), all staging via global_load_lds, COUNTED
// s_waitcnt vmcnt(9/8) + raw s_barrier (never drain to 0 in steady state).
// R1-R3 all stalled on full vmcnt(0) drains every K-step; here stage(t+1)
// stays in flight across the whole compute of tile t (~1200 cyc).
// LDS swizzle for 64B rows: byte ^= ((row>>1)&3)<<4 (derived: 8 distinct
// bank-groups per 16-lane ds_read_b128 = 2-way = free). Fused normalize kept.

#define N_ROWS 65536
#define K_CL   1024
#define D_DIM  512
#define BM     64
#define BK     32

typedef __attribute__((ext_vector_type(8))) short short8;
typedef __attribute__((ext_vector_type(4))) float f32x4;

__device__ __forceinline__ ushort f2bf(float f) {
    union { float f; uint32_t u; } v; v.f = f;
    uint32_t u = v.u;
    u += 0x7fffu + ((u >> 16) & 1u);   // RNE (inputs are finite normals)
    return (ushort)(u >> 16);
}

__device__ __forceinline__ float waveReduceSum(float s) {
#pragma unroll
    for (int off = 32; off; off >>= 1) s += __shfl_down(s, off, 64);
    return s;
}

// ---- prep: fp32 -> bf16 + row sum-of-squares (one wave per row of 512) ----
__global__ void prep_rows(const float* __restrict__ X, ushort* __restrict__ Xbf,
                          float* __restrict__ sq) {
    const int row  = blockIdx.x * 4 + (threadIdx.x >> 6);
    const int lane = threadIdx.x & 63;
    const float4* src = (const float4*)(X + (size_t)row * D_DIM);
    float4 a = src[lane * 2];
    float4 b = src[lane * 2 + 1];
    float s = (a.x*a.x + a.y*a.y) + (a.z*a.z + a.w*a.w)
            + (b.x*b.x + b.y*b.y) + (b.z*b.z + b.w*b.w);
    uint4 o;
    o.x = (uint32_t)f2bf(a.x) | ((uint32_t)f2bf(a.y) << 16);
    o.y = (uint32_t)f2bf(a.z) | ((uint32_t)f2bf(a.w) << 16);
    o.z = (uint32_t)f2bf(b.x) | ((uint32_t)f2bf(b.y) << 16);
    o.w = (uint32_t)f2bf(b.z) | ((uint32_t)f2bf(b.w) << 16);
    *(uint4*)(Xbf + (size_t)row * D_DIM + lane * 8) = o;
    s = waveReduceSum(s);
    if (lane == 0) sq[row] = s;
}

// ---- fused GEMM + numerator + row-normalize, counted-vmcnt pipeline ----
// Block: 64 rows x full K=1024, 512 threads (8 waves); wave w owns cluster
// cols [w*128, w*128+128). Per K-tile (BK=32): stage next tile (9 gload_lds),
// vmcnt(9), barrier, 12 ds_read + 32 MFMA.
__global__ __launch_bounds__(512, 2) void gemm_fused(
    const ushort* __restrict__ A, const ushort* __restrict__ B,
    const float* __restrict__ xsq, const float* __restrict__ csq,
    float* __restrict__ out)
{
    // [row][32] bf16 = 64 B rows; 16B slot s of row r holds global slot
    // s ^ ((r>>1)&3). 2x(4KB A + 64KB B) = 136 KB.
    __shared__ __align__(16) ushort smA[2][BM * BK];
    __shared__ __align__(16) ushort smB[2][K_CL * BK];

    const int tid  = threadIdx.x;
    const int w    = tid >> 6;
    const int lane = tid & 63;
    const int l4 = lane >> 4, l16 = lane & 15;
    const int rbase = blockIdx.x * BM;

    // staging source (per-lane; pre-swizzled so LDS dest is linear)
    const int gslot = (tid & 3) ^ ((tid >> 3) & 3);
    const int grow  = tid >> 2;                     // 0..127
    const ushort* srcA = A + (size_t)(rbase + grow) * D_DIM + gslot * 8; // tid<256
    const ushort* srcB = B + (size_t)grow * D_DIM + gslot * 8;  // + c*128 rows

    // read-side offsets (bytes); swizzle is lane-constant
    const int swz  = ((l16 >> 1) & 3) << 4;
    const int aoff = l16 * 64 + ((l4 * 16) ^ swz);               // + m*1024
    const int boff = (w * 128 + l16) * 64 + ((l4 * 16) ^ swz);   // + n*1024

    f32x4 acc[4][8] = {};

#define STAGE(sbuf, kt) do {                                                 \
        if (w < 4)                                                           \
            __builtin_amdgcn_global_load_lds(                                \
                (const __attribute__((address_space(1))) void*)(srcA + (kt)),\
                (__attribute__((address_space(3))) void*)(&smA[sbuf][0] + w * 512), \
                16, 0, 0);                                                   \
        _Pragma("unroll")                                                    \
        for (int c = 0; c < 8; ++c)                                          \
            __builtin_amdgcn_global_load_lds(                                \
                (const __attribute__((address_space(1))) void*)(srcB + (size_t)c * 128 * D_DIM + (kt)), \
                (__attribute__((address_space(3))) void*)(&smB[sbuf][0] + c * 4096 + w * 512), \
                16, 0, 0);                                                   \
    } while (0)

    STAGE(0, 0);   // prologue: tile 0 in flight

    for (int t = 0; t < 16; ++t) {
        const int buf = t & 1;
        __builtin_amdgcn_sched_barrier(0);
        __builtin_amdgcn_s_barrier();          // BAR A: dest buffer free
        __builtin_amdgcn_sched_barrier(0);
        if (t < 15) {
            STAGE(buf ^ 1, (t + 1) * BK);
            // own stage(t) ops (issued one full tile ago) must be complete;
            // keep the 9/8 just-issued stage(t+1) ops in flight.
            if (w < 4) asm volatile("s_waitcnt vmcnt(9)" ::: "memory");
            else       asm volatile("s_waitcnt vmcnt(8)" ::: "memory");
        } else {
            asm volatile("s_waitcnt vmcnt(0)" ::: "memory");
        }
        __builtin_amdgcn_s_barrier();          // BAR B: all waves staged tile t
        __builtin_amdgcn_sched_barrier(0);

        const char* bA = (const char*)&smA[buf][0];
        const char* bB = (const char*)&smB[buf][0];
        short8 af[4], bf[8];
#pragma unroll
        for (int m = 0; m < 4; ++m)
            af[m] = *(const short8*)(bA + m * 1024 + aoff);
#pragma unroll
        for (int n = 0; n < 8; ++n)
            bf[n] = *(const short8*)(bB + n * 1024 + boff);

        __builtin_amdgcn_s_setprio(1);
#pragma unroll
        for (int m = 0; m < 4; ++m)
#pragma unroll
            for (int n = 0; n < 8; ++n)
                acc[m][n] = __builtin_amdgcn_mfma_f32_16x16x32_bf16(
                    af[m], bf[n], acc[m][n], 0, 0, 0);
        __builtin_amdgcn_s_setprio(0);
    }
#undef STAGE

    __syncthreads();   // before reusing smA[0] as reduction scratch

    // ---- epilogue: numerator + fused row-normalize ----
    // C/D layout: col = l16, row = l4*4 + reg (per 16x16 frag)
    float xs[4][4];
#pragma unroll
    for (int m = 0; m < 4; ++m)
#pragma unroll
        for (int r = 0; r < 4; ++r)
            xs[m][r] = xsq[rbase + m * 16 + l4 * 4 + r];

    float s[4][4] = {{0.f}};
#pragma unroll
    for (int n = 0; n < 8; ++n) {
        const float cs = csq[w * 128 + n * 16 + l16];
#pragma unroll
        for (int m = 0; m < 4; ++m)
#pragma unroll
            for (int r = 0; r < 4; ++r) {
                float ns = fmaxf(xs[m][r] - 2.0f * acc[m][n][r] + cs, 0.0f);
                float p = 1.0f / (1.0f + ns);
                acc[m][n][r] = p;
                s[m][r] += p;
            }
    }
    // reduce across the 16 col-lanes of each 16-lane group
#pragma unroll
    for (int m = 0; m < 4; ++m)
#pragma unroll
        for (int r = 0; r < 4; ++r) {
            float v = s[m][r];
            v += __shfl_xor(v, 1, 64);
            v += __shfl_xor(v, 2, 64);
            v += __shfl_xor(v, 4, 64);
            v += __shfl_xor(v, 8, 64);
            s[m][r] = v;
        }
    // cross-wave reduce via LDS (alias smA[0]; barriers above protect)
    float* smRS  = (float*)&smA[0][0];         // [8 waves][64 rows]
    float* smInv = (float*)&smA[0][0] + 512;   // [64]
    if (l16 == 0) {
#pragma unroll
        for (int m = 0; m < 4; ++m)
#pragma unroll
            for (int r = 0; r < 4; ++r)
                smRS[w * 64 + m * 16 + l4 * 4 + r] = s[m][r];
    }
    __syncthreads();
    if (tid < 64) {
        float t = 0.f;
#pragma unroll
        for (int j = 0; j < 8; ++j) t += smRS[j * 64 + tid];
        smInv[tid] = 1.0f / t;
    }
    __syncthreads();

    float inv[4][4];
#pragma unroll
    for (int m = 0; m < 4; ++m)
#pragma unroll
        for (int r = 0; r < 4; ++r)
            inv[m][r] = smInv[m * 16 + l4 * 4 + r];   // broadcast read

#pragma unroll
    for (int m = 0; m < 4; ++m)
#pragma unroll
        for (int n = 0; n < 8; ++n) {
            const int col = w * 128 + n * 16 + l16;
#pragma unroll
            for (int r = 0; r < 4; ++r) {
                const int row = rbase + m * 16 + l4 * 4 + r;
                out[(size_t)row * K_CL + col] = acc[m][n][r] * inv[m][r];
            }
        }
}

extern "C" void kernel_launch(void* const* d_in, const int* in_sizes, int n_in,
                              void* d_out, int out_size, void* d_ws, size_t ws_size,
                              hipStream_t stream) {
    const float* batch   = (const float*)d_in[0];
    const float* centers = (const float*)d_in[1];
    float* out = (float*)d_out;

    char* ws = (char*)d_ws;
    ushort* Abf = (ushort*)ws;                                          // 64 MB
    ushort* Bbf = (ushort*)(ws + (size_t)N_ROWS * D_DIM * 2);          // 1 MB
    float*  xsq = (float*)(ws + (size_t)N_ROWS * D_DIM * 2
                              + (size_t)K_CL * D_DIM * 2);             // 256 KB
    float*  csq = xsq + N_ROWS;                                         // 4 KB
    (void)in_sizes; (void)n_in; (void)out_size; (void)ws_size;

    prep_rows<<<K_CL / 4,   256, 0, stream>>>(centers, Bbf, csq);
    prep_rows<<<N_ROWS / 4, 256, 0, stream>>>(batch, Abf, xsq);
    gemm_fused<<<N_ROWS / BM, 512, 0, stream>>>(Abf, Bbf, xsq, csq, out);
}